// Round 7
// baseline (3024.658 us; speedup 1.0000x reference)
//
#include <hip/hip_runtime.h>

#define N_NODES 100000
#define D_FEAT 128
#define EPS_NORM 1e-12f

// ---------------------------------------------------------------------------
// d_out is FLOAT32 (= reference output dtype; rounds 0-6 decoded this):
//   h_out : f32 [N,128]  at d_out[0 .. 12.8M)
//   b_out : f32 [N,256]  at d_out[12.8M .. 38.4M)   ("bund")
// Scratch is folded into bund:
//   bund[n][128+d] accumulates the c-sum (its final pre-normalize location)
//   bund[n][0]     accumulates the in-degree (b-half is dead until finalize,
//                  which reads b from the INPUT; row n is block-private)
// No d_ws usage. Every output element is written every call (poison-safe).
// ---------------------------------------------------------------------------

// K1: zero the whole bundle region (N*256 f32).
__global__ void zero_r7(float4* __restrict__ bund4) {
    int i = blockIdx.x * blockDim.x + threadIdx.x;
    if (i < N_NODES * (2 * D_FEAT / 4))
        bund4[i] = make_float4(0.f, 0.f, 0.f, 0.f);
}

// K2: scatter. One thread per (edge, 4-feature group); 32 threads/edge.
// bund[dst][128 + q*4 .. +4) += h[src][q*4 .. +4) * norm[src]
// lane q==0: bund[dst][0] += 1 (degree).
__global__ void scatter_r7(const float4* __restrict__ h4,
                           const float* __restrict__ norm,
                           const int* __restrict__ edge_src,
                           const int* __restrict__ edge_dst,
                           float* __restrict__ bund, int E) {
    long long tid = (long long)blockIdx.x * blockDim.x + threadIdx.x;
    int e = (int)(tid >> 5);
    int q = (int)(tid & 31);
    if (e >= E) return;
    int s = edge_src[e];
    int t = edge_dst[e];
    float nm = norm[s];
    float4 v = h4[s * (D_FEAT / 4) + q];
    float* cp = bund + (long long)t * (2 * D_FEAT) + D_FEAT + q * 4;
    atomicAdd(cp + 0, v.x * nm);
    atomicAdd(cp + 1, v.y * nm);
    atomicAdd(cp + 2, v.z * nm);
    atomicAdd(cp + 3, v.w * nm);
    if (q == 0) atomicAdd(bund + (long long)t * (2 * D_FEAT), 1.0f);
}

// K3: one 256-thread block per node n.
//   deg   = bund[n][0] (read by all lanes BEFORE the barrier)
//   cmean = bund[n][128+d]/deg ; h_out[n][d] = h[n][d] + cmean*norm[n]
//   b_out[n][:] = concat(b[n], cmean) / l2           (written AFTER barrier)
__global__ void finalize_r7(const float* __restrict__ h,
                            const float* __restrict__ b,
                            const float* __restrict__ norm,
                            float* __restrict__ h_out,
                            float* __restrict__ bund) {
    int n = blockIdx.x;
    int t = threadIdx.x;  // 0..255

    float invdeg = 1.0f / fmaxf(rintf(bund[n * (2 * D_FEAT)]), 1.0f);
    float nm = norm[n];

    float val;
    if (t < D_FEAT) {
        val = b[n * D_FEAT + t];
    } else {
        int d = t - D_FEAT;
        val = bund[n * (2 * D_FEAT) + t] * invdeg;       // read before barrier
        h_out[n * D_FEAT + d] = h[n * D_FEAT + d] + val * nm;
    }

    // Block-wide sum of squares over 256 lanes: wave-64 butterfly + LDS.
    float sq = val * val;
    #pragma unroll
    for (int m = 1; m < 64; m <<= 1) sq += __shfl_xor(sq, m, 64);

    __shared__ float red[4];
    int wid = t >> 6;
    int lane = t & 63;
    if (lane == 0) red[wid] = sq;
    __syncthreads();            // orders all bund reads before all bund writes
    float total = red[0] + red[1] + red[2] + red[3];

    float rinv = 1.0f / fmaxf(sqrtf(total), EPS_NORM);
    bund[n * (2 * D_FEAT) + t] = val * rinv;             // write after barrier
}

extern "C" void kernel_launch(void* const* d_in, const int* in_sizes, int n_in,
                              void* d_out, int out_size, void* d_ws, size_t ws_size,
                              hipStream_t stream) {
    const float* h = (const float*)d_in[0];
    const float* b = (const float*)d_in[1];
    const float* norm = (const float*)d_in[2];
    const int* edge_src = (const int*)d_in[3];
    const int* edge_dst = (const int*)d_in[4];
    int E = in_sizes[3];

    float* h_out = (float*)d_out;                        // f32 [N,128]
    float* bund = (float*)d_out + (size_t)N_NODES * D_FEAT;  // f32 [N,256]

    int zthreads = N_NODES * (2 * D_FEAT / 4);           // 6.4M
    zero_r7<<<(zthreads + 255) / 256, 256, 0, stream>>>((float4*)bund);

    long long total_threads = (long long)E * 32;
    int blocks = (int)((total_threads + 255) / 256);
    scatter_r7<<<blocks, 256, 0, stream>>>((const float4*)h, norm,
                                           edge_src, edge_dst, bund, E);

    finalize_r7<<<N_NODES, 256, 0, stream>>>(h, b, norm, h_out, bund);
}